// Round 8
// baseline (249.400 us; speedup 1.0000x reference)
//
#include <hip/hip_runtime.h>
#include <stdint.h>

#define B_SZ 32
#define C_SZ 64
#define N_SZ 65536
#define K_SZ 8192
#define BCAP 384   // fixed per-bucket capacity (Poisson(256), ~8 sigma; verified)
#define NHEAD 48   // head buckets for round 2 (verified: base(48) >= K)
#define JCAP 80    // per j-bucket capacity (verified no overflow)

__device__ __forceinline__ uint32_t rotl32(uint32_t v, int r) {
  return (v << r) | (v >> (32 - r));
}

// JAX Threefry-2x32, 20 rounds.
__device__ __forceinline__ void threefry2x32(uint32_t k0, uint32_t k1,
                                             uint32_t x0, uint32_t x1,
                                             uint32_t& o0, uint32_t& o1) {
  const uint32_t ks2 = k0 ^ k1 ^ 0x1BD11BDAu;
  x0 += k0; x1 += k1;
#define TF_R(r) { x0 += x1; x1 = rotl32(x1, (r)); x1 ^= x0; }
  TF_R(13) TF_R(15) TF_R(26) TF_R(6)   x0 += k1;  x1 += ks2 + 1u;
  TF_R(17) TF_R(29) TF_R(16) TF_R(24)  x0 += ks2; x1 += k0  + 2u;
  TF_R(13) TF_R(15) TF_R(26) TF_R(6)   x0 += k0;  x1 += k1  + 3u;
  TF_R(17) TF_R(29) TF_R(16) TF_R(24)  x0 += k1;  x1 += ks2 + 4u;
  TF_R(13) TF_R(15) TF_R(26) TF_R(6)   x0 += ks2; x1 += k0  + 5u;
#undef TF_R
  o0 = x0; o1 = x1;
}

__device__ __forceinline__ void subkey_for_round(int b, int round,
                                                 uint32_t& sk0, uint32_t& sk1) {
  uint32_t c0, c1;
  threefry2x32(0u, 1u, 0u, (uint32_t)b, c0, c1);
  for (int r = 0; r < round; ++r) {
    uint32_t n0, n1;
    threefry2x32(c0, c1, 0u, 0u, n0, n1);
    c0 = n0; c1 = n1;
  }
  threefry2x32(c0, c1, 0u, 1u, sk0, sk1);
}

// zero cnt1 (32 KiB). cnt2/jcnt are zeroed inside prefix1/prefix2.
__global__ __launch_bounds__(256) void zero_cnt(uint32_t* __restrict__ z) {
  z[blockIdx.x * 256 + threadIdx.x] = 0;
}

// round-1: keygen (recomputed, nothing staged) + direct fixed-cap bucket scatter.
__global__ __launch_bounds__(256) void gen_scatter1(uint64_t* __restrict__ BVfix,
                                                    uint32_t* __restrict__ cnt1) {
  __shared__ uint32_t lcnt[256];
  __shared__ uint32_t gb[256];
  const int t = threadIdx.x, chunk = blockIdx.x, b = blockIdx.y;
  lcnt[t] = 0; __syncthreads();
  uint32_t sk0, sk1;
  subkey_for_round(b, 0, sk0, sk1);
  uint64_t v[16]; uint32_t r[16], dg[16];
  const int base = chunk * 4096;
#pragma unroll
  for (int e = 0; e < 16; ++e) {
    const int i = base + e * 256 + t;
    uint32_t o0, o1;
    threefry2x32(sk0, sk1, 0u, (uint32_t)i, o0, o1);
    const uint32_t bits = o0 ^ o1;
    v[e] = ((uint64_t)bits << 16) | (uint64_t)i;
    dg[e] = bits >> 24;
    r[e] = atomicAdd(&lcnt[dg[e]], 1u);
  }
  __syncthreads();
  if (lcnt[t]) gb[t] = atomicAdd(&cnt1[b * 256 + t], lcnt[t]);
  __syncthreads();
#pragma unroll
  for (int e = 0; e < 16; ++e) {
    const uint32_t slot = gb[dg[e]] + r[e];
    if (slot < BCAP)
      BVfix[((size_t)(b * 256 + dg[e])) * BCAP + slot] = v[e];
  }
}

// per-batch exclusive scan of 256 bucket counts -> baseArr(257). Zeroes cnt2.
__global__ __launch_bounds__(256) void prefix1(const uint32_t* __restrict__ cnt1,
                                               uint32_t* __restrict__ baseArr,
                                               uint32_t* __restrict__ cnt2) {
  __shared__ uint32_t sc[256];
  const int b = blockIdx.x, d = threadIdx.x;
  cnt2[b * 256 + d] = 0;
  uint32_t h = cnt1[b * 256 + d];
  if (h > BCAP) h = BCAP;
  sc[d] = h; __syncthreads();
  for (int off = 1; off < 256; off <<= 1) {
    const uint32_t y = (d >= off) ? sc[d - off] : 0u;
    __syncthreads();
    sc[d] += y;
    __syncthreads();
  }
  baseArr[b * 257 + d] = sc[d] - h;
  if (d == 255) baseArr[b * 257 + 256] = sc[255];
}

// Brute-force rank of one bucket: all records share the top-8 key bits, so the
// packed u64 (key32<<16|pos) IS the lexicographic (key,pos) sort key; rank =
// count of smaller u64s via LDS broadcast reads (conflict-free). One barrier.
// Writes S1v[global rank] = pos.
__global__ __launch_bounds__(256) void rank_sort1(const uint64_t* __restrict__ BVfix,
                                                  const uint32_t* __restrict__ cnt1,
                                                  const uint32_t* __restrict__ baseArr,
                                                  uint16_t* __restrict__ S1v) {
  __shared__ uint64_t s[BCAP];
  const int t = threadIdx.x, u = blockIdx.x, b = blockIdx.y;
  uint32_t n = cnt1[b * 256 + u];
  if (n > BCAP) n = BCAP;
  const uint64_t* __restrict__ g = BVfix + ((size_t)(b * 256 + u)) * BCAP;
  uint64_t my0 = ~0ull, my1 = ~0ull;
  if (t < (int)n)       { my0 = g[t];       s[t] = my0; }
  if (t + 256 < (int)n) { my1 = g[t + 256]; s[t + 256] = my1; }
  __syncthreads();
  uint32_t r0 = 0, r1 = 0;
#pragma unroll 4
  for (uint32_t i = 0; i < n; ++i) {
    const uint64_t si = s[i];
    r0 += (si < my0) ? 1u : 0u;
    r1 += (si < my1) ? 1u : 0u;
  }
  const uint32_t base = baseArr[b * 257 + u];
  uint16_t* __restrict__ out = S1v + (size_t)b * N_SZ + base;
  if (t < (int)n)       out[r0] = (uint16_t)(my0 & 0xFFFFull);
  if (t + 256 < (int)n) out[r1] = (uint16_t)(my1 & 0xFFFFull);
}

// round-2: keygen + direct scatter of head buckets (u < NHEAD) only.
__global__ __launch_bounds__(256) void gen_scatter2(uint64_t* __restrict__ CVfix,
                                                    uint32_t* __restrict__ cnt2) {
  __shared__ uint32_t lcnt[256];
  __shared__ uint32_t gb[256];
  const int t = threadIdx.x, chunk = blockIdx.x, b = blockIdx.y;
  lcnt[t] = 0; __syncthreads();
  uint32_t sk0, sk1;
  subkey_for_round(b, 1, sk0, sk1);
  uint64_t v[16]; uint32_t r[16], dg[16];
  const int base = chunk * 4096;
#pragma unroll
  for (int e = 0; e < 16; ++e) {
    const int i = base + e * 256 + t;
    uint32_t o0, o1;
    threefry2x32(sk0, sk1, 0u, (uint32_t)i, o0, o1);
    const uint32_t bits = o0 ^ o1;
    v[e] = ((uint64_t)bits << 16) | (uint64_t)i;
    dg[e] = bits >> 24;
    r[e] = (dg[e] < NHEAD) ? atomicAdd(&lcnt[dg[e]], 1u) : 0u;
  }
  __syncthreads();
  if (t < NHEAD && lcnt[t]) gb[t] = atomicAdd(&cnt2[b * 256 + t], lcnt[t]);
  __syncthreads();
#pragma unroll
  for (int e = 0; e < 16; ++e) {
    if (dg[e] < NHEAD) {
      const uint32_t slot = gb[dg[e]] + r[e];
      if (slot < BCAP)
        CVfix[((size_t)(b * NHEAD + dg[e])) * BCAP + slot] = v[e];
    }
  }
}

// per-batch exclusive scan over the NHEAD counted buckets. Zeroes jcnt.
__global__ __launch_bounds__(256) void prefix2(const uint32_t* __restrict__ cnt2,
                                               uint32_t* __restrict__ baseArr2,
                                               uint32_t* __restrict__ jcnt) {
  __shared__ uint32_t sc[256];
  const int b = blockIdx.x, d = threadIdx.x;
  jcnt[b * 256 + d] = 0;
  uint32_t h = 0;
  if (d < NHEAD) { h = cnt2[b * 256 + d]; if (h > BCAP) h = BCAP; }
  sc[d] = h; __syncthreads();
  for (int off = 1; off < 256; off <<= 1) {
    const uint32_t y = (d >= off) ? sc[d - off] : 0u;
    __syncthreads();
    sc[d] += y;
    __syncthreads();
  }
  if (d < NHEAD) baseArr2[b * NHEAD + d] = sc[d] - h;
}

// brute-force rank head buckets of round 2; emit (j<<16)|q pairs into j-buckets.
__global__ __launch_bounds__(256) void finalize_rank(const uint64_t* __restrict__ CVfix,
                                                     const uint32_t* __restrict__ cnt2,
                                                     const uint32_t* __restrict__ baseArr2,
                                                     const uint16_t* __restrict__ S1v,
                                                     uint32_t* __restrict__ jcnt,
                                                     uint32_t* __restrict__ jb) {
  __shared__ uint64_t s[BCAP];
  const int t = threadIdx.x, u = blockIdx.x, b = blockIdx.y;
  const uint32_t base = baseArr2[b * NHEAD + u];
  if (base >= K_SZ) return;
  uint32_t n = cnt2[b * 256 + u];
  if (n > BCAP) n = BCAP;
  const uint64_t* __restrict__ g = CVfix + ((size_t)(b * NHEAD + u)) * BCAP;
  uint64_t my0 = ~0ull, my1 = ~0ull;
  if (t < (int)n)       { my0 = g[t];       s[t] = my0; }
  if (t + 256 < (int)n) { my1 = g[t + 256]; s[t + 256] = my1; }
  __syncthreads();
  uint32_t r0 = 0, r1 = 0;
#pragma unroll 4
  for (uint32_t i = 0; i < n; ++i) {
    const uint64_t si = s[i];
    r0 += (si < my0) ? 1u : 0u;
    r1 += (si < my1) ? 1u : 0u;
  }
  const uint16_t* __restrict__ s1 = S1v + (size_t)b * N_SZ;
#pragma unroll
  for (int w = 0; w < 2; ++w) {
    const int e = t + w * 256;
    const uint32_t r = w ? r1 : r0;
    const uint64_t my = w ? my1 : my0;
    if (e < (int)n) {
      const uint32_t q = base + r;
      if (q < K_SZ) {
        const uint32_t p = (uint32_t)(my & 0xFFFFull);   // round-1 rank index
        const uint32_t j = (uint32_t)s1[p];              // permutation value
        const uint32_t slot = atomicAdd(&jcnt[b * 256 + (j >> 8)], 1u);
        if (slot < JCAP)
          jb[((size_t)b * 256 + (j >> 8)) * JCAP + slot] = (j << 16) | q;
      }
    }
  }
}

// compact capped j-buckets into dense bucket-ordered pair list sp[b][0..K).
__global__ __launch_bounds__(256) void compact_pairs(const uint32_t* __restrict__ jcnt,
                                                     const uint32_t* __restrict__ jb,
                                                     uint32_t* __restrict__ sp) {
  __shared__ uint32_t sc[256];
  __shared__ uint32_t cnt[256];
  const int b = blockIdx.x, t = threadIdx.x;
  uint32_t c = jcnt[b * 256 + t];
  if (c > JCAP) c = JCAP;
  cnt[t] = c; sc[t] = c;
  __syncthreads();
  for (int off = 1; off < 256; off <<= 1) {
    const uint32_t y = (t >= off) ? sc[t - off] : 0u;
    __syncthreads();
    sc[t] += y;
    __syncthreads();
  }
  const uint32_t base = sc[t] - cnt[t];
  const uint32_t* __restrict__ src = jb + ((size_t)b * 256 + t) * JCAP;
  uint32_t* __restrict__ dst = sp + (size_t)b * K_SZ + base;
  for (uint32_t i = 0; i < cnt[t]; ++i) dst[i] = src[i];
}

// gather: one (b,c) row per block. Random LDS writes, coalesced float4 stores.
__global__ __launch_bounds__(256) void gather_staged(const float* __restrict__ x,
                                                     const uint32_t* __restrict__ sp,
                                                     float* __restrict__ y) {
  __shared__ float row[K_SZ];   // 32 KiB
  const int t = threadIdx.x, c = blockIdx.x, b = blockIdx.y;
  const uint32_t* __restrict__ spb = sp + (size_t)b * K_SZ;
  const float* __restrict__ xr = x + ((size_t)b * C_SZ + c) * N_SZ;
#pragma unroll 8
  for (int w = 0; w < 32; ++w) {
    const uint32_t p = spb[w * 256 + t];
    row[p & 0xFFFFu] = xr[p >> 16];
  }
  __syncthreads();
  float4* __restrict__ yr4 = (float4*)(y + ((size_t)b * C_SZ + c) * K_SZ);
  const float4* __restrict__ r4 = (const float4*)row;
#pragma unroll
  for (int w = 0; w < 8; ++w) yr4[w * 256 + t] = r4[w * 256 + t];
}

extern "C" void kernel_launch(void* const* d_in, const int* in_sizes, int n_in,
                              void* d_out, int out_size, void* d_ws, size_t ws_size,
                              hipStream_t stream) {
  (void)in_sizes; (void)n_in; (void)out_size; (void)ws_size;
  const float* x = (const float*)d_in[0];
  float* y = (float*)d_out;

  // d_out (64 MiB) scratch; gather fully overwrites it and reads only x + d_ws.
  char* base = (char*)d_out;
  uint64_t* BVfix = (uint64_t*)base;                      // 24 MiB fixed-cap round-1 buckets
  uint64_t* CVfix = (uint64_t*)(base + (26u << 20));      // 4.5 MiB fixed-cap round-2 head buckets
  uint16_t* S1v   = (uint16_t*)(base + (31u << 20));      // 4 MiB u16 value table
  uint32_t* baseArr  = (uint32_t*)(base + (36u << 20));   // 33 KiB
  uint32_t* baseArr2 = (uint32_t*)(base + (37u << 20));   // 6 KiB
  // d_ws: [cnt1 32K | cnt2 32K | jcnt 32K | pad | jb | sp]
  uint32_t* cnt1 = (uint32_t*)d_ws;
  uint32_t* cnt2 = (uint32_t*)((char*)d_ws + (32u << 10));
  uint32_t* jcnt = (uint32_t*)((char*)d_ws + (64u << 10));
  uint32_t* jb   = (uint32_t*)((char*)d_ws + (128u << 10));   // 2.62 MiB
  uint32_t* sp   = (uint32_t*)((char*)d_ws + (4u << 20));     // 1 MiB

  const dim3 blk(256);
  const dim3 ggen(16, B_SZ);

  zero_cnt<<<dim3(B_SZ), blk, 0, stream>>>(cnt1);
  // round 1
  gen_scatter1<<<ggen, blk, 0, stream>>>(BVfix, cnt1);
  prefix1<<<dim3(B_SZ), blk, 0, stream>>>(cnt1, baseArr, cnt2);
  rank_sort1<<<dim3(256, B_SZ), blk, 0, stream>>>(BVfix, cnt1, baseArr, S1v);
  // round 2
  gen_scatter2<<<ggen, blk, 0, stream>>>(CVfix, cnt2);
  prefix2<<<dim3(B_SZ), blk, 0, stream>>>(cnt2, baseArr2, jcnt);
  finalize_rank<<<dim3(NHEAD, B_SZ), blk, 0, stream>>>(CVfix, cnt2, baseArr2, S1v, jcnt, jb);
  compact_pairs<<<dim3(B_SZ), blk, 0, stream>>>(jcnt, jb, sp);
  // gather
  gather_staged<<<dim3(C_SZ, B_SZ), blk, 0, stream>>>(x, sp, y);
}

// Round 10
// 193.380 us; speedup vs baseline: 1.2897x; 1.2897x over previous
//
#include <hip/hip_runtime.h>
#include <stdint.h>

#define B_SZ 32
#define C_SZ 64
#define N_SZ 65536
#define K_SZ 8192
#define BCAP 384   // fixed per-bucket capacity (Poisson(256), ~8 sigma; verified)
#define NHEAD 48   // head buckets for round 2 (verified: base(48) >= K)
#define JCAP 80    // per j-bucket capacity (verified no overflow)

__device__ __forceinline__ uint32_t rotl32(uint32_t v, int r) {
  return (v << r) | (v >> (32 - r));
}

// JAX Threefry-2x32, 20 rounds.
__device__ __forceinline__ void threefry2x32(uint32_t k0, uint32_t k1,
                                             uint32_t x0, uint32_t x1,
                                             uint32_t& o0, uint32_t& o1) {
  const uint32_t ks2 = k0 ^ k1 ^ 0x1BD11BDAu;
  x0 += k0; x1 += k1;
#define TF_R(r) { x0 += x1; x1 = rotl32(x1, (r)); x1 ^= x0; }
  TF_R(13) TF_R(15) TF_R(26) TF_R(6)   x0 += k1;  x1 += ks2 + 1u;
  TF_R(17) TF_R(29) TF_R(16) TF_R(24)  x0 += ks2; x1 += k0  + 2u;
  TF_R(13) TF_R(15) TF_R(26) TF_R(6)   x0 += k0;  x1 += k1  + 3u;
  TF_R(17) TF_R(29) TF_R(16) TF_R(24)  x0 += k1;  x1 += ks2 + 4u;
  TF_R(13) TF_R(15) TF_R(26) TF_R(6)   x0 += ks2; x1 += k0  + 5u;
#undef TF_R
  o0 = x0; o1 = x1;
}

__device__ __forceinline__ void subkey_for_round(int b, int round,
                                                 uint32_t& sk0, uint32_t& sk1) {
  uint32_t c0, c1;
  threefry2x32(0u, 1u, 0u, (uint32_t)b, c0, c1);
  for (int r = 0; r < round; ++r) {
    uint32_t n0, n1;
    threefry2x32(c0, c1, 0u, 0u, n0, n1);
    c0 = n0; c1 = n1;
  }
  threefry2x32(c0, c1, 0u, 1u, sk0, sk1);
}

// 256-wide exclusive scan using per-wave shfl scans + 1 barrier.
__device__ __forceinline__ uint32_t block_excl_scan(uint32_t h, int t,
                                                    uint32_t* __restrict__ wsum) {
  const int lane = t & 63, w = t >> 6;
  uint32_t inc = h;
#pragma unroll
  for (int off = 1; off < 64; off <<= 1) {
    const uint32_t y = __shfl_up(inc, off, 64);
    if (lane >= off) inc += y;
  }
  if (lane == 63) wsum[w] = inc;
  __syncthreads();
  uint32_t woff = 0;
#pragma unroll
  for (int w2 = 0; w2 < 4; ++w2)
    if (w2 < w) woff += wsum[w2];
  return woff + inc - h;
}

// zero cnt1 (32 KiB). cnt2/jcnt are zeroed inside prefix1/prefix2.
__global__ __launch_bounds__(256) void zero_cnt(uint32_t* __restrict__ z) {
  z[blockIdx.x * 256 + threadIdx.x] = 0;
}

// round-1: keygen (recomputed, nothing staged) + direct fixed-cap bucket scatter.
__global__ __launch_bounds__(256) void gen_scatter1(uint64_t* __restrict__ BVfix,
                                                    uint32_t* __restrict__ cnt1) {
  __shared__ uint32_t lcnt[256];
  __shared__ uint32_t gb[256];
  const int t = threadIdx.x, chunk = blockIdx.x, b = blockIdx.y;
  lcnt[t] = 0; __syncthreads();
  uint32_t sk0, sk1;
  subkey_for_round(b, 0, sk0, sk1);
  uint64_t v[16]; uint32_t r[16], dg[16];
  const int base = chunk * 4096;
#pragma unroll
  for (int e = 0; e < 16; ++e) {
    const int i = base + e * 256 + t;
    uint32_t o0, o1;
    threefry2x32(sk0, sk1, 0u, (uint32_t)i, o0, o1);
    const uint32_t bits = o0 ^ o1;
    v[e] = ((uint64_t)bits << 16) | (uint64_t)i;
    dg[e] = bits >> 24;
    r[e] = atomicAdd(&lcnt[dg[e]], 1u);
  }
  __syncthreads();
  if (lcnt[t]) gb[t] = atomicAdd(&cnt1[b * 256 + t], lcnt[t]);
  __syncthreads();
#pragma unroll
  for (int e = 0; e < 16; ++e) {
    const uint32_t slot = gb[dg[e]] + r[e];
    if (slot < BCAP)
      BVfix[((size_t)(b * 256 + dg[e])) * BCAP + slot] = v[e];
  }
}

// per-batch exclusive scan of 256 bucket counts -> baseArr(257). Zeroes cnt2.
__global__ __launch_bounds__(256) void prefix1(const uint32_t* __restrict__ cnt1,
                                               uint32_t* __restrict__ baseArr,
                                               uint32_t* __restrict__ cnt2) {
  __shared__ uint32_t wsum[4];
  const int b = blockIdx.x, d = threadIdx.x;
  cnt2[b * 256 + d] = 0;
  uint32_t h = cnt1[b * 256 + d];
  if (h > BCAP) h = BCAP;
  const uint32_t excl = block_excl_scan(h, d, wsum);
  baseArr[b * 257 + d] = excl;
  if (d == 255) baseArr[b * 257 + 256] = excl + h;
}

// Two-level counting-rank of one bucket (n<=BCAP): digit2 = key bits 23..16
// (256 groups, lambda~1); within group rank by sub = (key_low16<<16)|pos.
// Order == stable sort by full key (pos tiebreak). Writes S1v[rank] = pos.
__global__ __launch_bounds__(256) void rank_sort1(const uint64_t* __restrict__ BVfix,
                                                  const uint32_t* __restrict__ cnt1,
                                                  const uint32_t* __restrict__ baseArr,
                                                  uint16_t* __restrict__ S1v) {
  __shared__ uint32_t sub[BCAP];
  __shared__ uint16_t dg[BCAP];
  __shared__ uint16_t idxt[BCAP];
  __shared__ uint32_t hist[256];
  __shared__ uint32_t cur[256];
  __shared__ uint32_t base2[257];
  __shared__ uint32_t wsum[4];
  const int t = threadIdx.x, u = blockIdx.x, b = blockIdx.y;
  uint32_t n = cnt1[b * 256 + u];
  if (n > BCAP) n = BCAP;
  const uint64_t* __restrict__ g = BVfix + ((size_t)(b * 256 + u)) * BCAP;
  const uint32_t base = baseArr[b * 257 + u];

  hist[t] = 0; __syncthreads();
  uint64_t rec[2] = {0, 0};
#pragma unroll
  for (int w = 0; w < 2; ++w) {
    const int e = t + w * 256;
    if (e < (int)n) {
      rec[w] = g[e];
      const uint32_t key = (uint32_t)(rec[w] >> 16);
      const uint32_t d = (key >> 16) & 0xFFu;
      sub[e] = ((key & 0xFFFFu) << 16) | (uint32_t)(rec[w] & 0xFFFFull);
      dg[e] = (uint16_t)d;
      atomicAdd(&hist[d], 1u);
    }
  }
  __syncthreads();
  const uint32_t h = hist[t];
  const uint32_t excl = block_excl_scan(h, t, wsum);
  base2[t] = excl;
  cur[t] = excl;
  if (t == 255) base2[256] = excl + h;
  __syncthreads();
#pragma unroll
  for (int w = 0; w < 2; ++w) {
    const int e = t + w * 256;
    if (e < (int)n) idxt[atomicAdd(&cur[dg[e]], 1u)] = (uint16_t)e;
  }
  __syncthreads();
  uint16_t* __restrict__ out = S1v + (size_t)b * N_SZ + base;
#pragma unroll
  for (int w = 0; w < 2; ++w) {
    const int e = t + w * 256;
    if (e < (int)n) {
      const uint32_t d = dg[e], s = sub[e];
      const uint32_t lo = base2[d], hi = base2[d + 1];
      uint32_t r = 0;
      for (uint32_t i = lo; i < hi; ++i) r += (sub[idxt[i]] < s) ? 1u : 0u;
      out[lo + r] = (uint16_t)(rec[w] & 0xFFFFull);
    }
  }
}

// round-2: keygen + direct scatter of head buckets (u < NHEAD) only.
// Packs rec = (key32<<32) | (i<<16) | j : i (round-2 index) is the STABLE
// TIEBREAK (must match JAX stable sort); j = S1v[i] (coalesced read) rides
// along so finalize needs no random gather.
__global__ __launch_bounds__(256) void gen_scatter2(const uint16_t* __restrict__ S1v,
                                                    uint64_t* __restrict__ CVfix,
                                                    uint32_t* __restrict__ cnt2) {
  __shared__ uint32_t lcnt[256];
  __shared__ uint32_t gb[256];
  const int t = threadIdx.x, chunk = blockIdx.x, b = blockIdx.y;
  lcnt[t] = 0; __syncthreads();
  uint32_t sk0, sk1;
  subkey_for_round(b, 1, sk0, sk1);
  const uint16_t* __restrict__ s1 = S1v + (size_t)b * N_SZ;
  uint64_t v[16]; uint32_t r[16], dg[16];
  const int base = chunk * 4096;
#pragma unroll
  for (int e = 0; e < 16; ++e) {
    const int i = base + e * 256 + t;
    uint32_t o0, o1;
    threefry2x32(sk0, sk1, 0u, (uint32_t)i, o0, o1);
    const uint32_t bits = o0 ^ o1;
    dg[e] = bits >> 24;
    if (dg[e] < NHEAD) {
      v[e] = ((uint64_t)bits << 32) | ((uint64_t)(uint32_t)i << 16) | (uint64_t)s1[i];
      r[e] = atomicAdd(&lcnt[dg[e]], 1u);
    }
  }
  __syncthreads();
  if (t < NHEAD && lcnt[t]) gb[t] = atomicAdd(&cnt2[b * 256 + t], lcnt[t]);
  __syncthreads();
#pragma unroll
  for (int e = 0; e < 16; ++e) {
    if (dg[e] < NHEAD) {
      const uint32_t slot = gb[dg[e]] + r[e];
      if (slot < BCAP)
        CVfix[((size_t)(b * NHEAD + dg[e])) * BCAP + slot] = v[e];
    }
  }
}

// per-batch exclusive scan over the NHEAD counted buckets. Zeroes jcnt.
__global__ __launch_bounds__(256) void prefix2(const uint32_t* __restrict__ cnt2,
                                               uint32_t* __restrict__ baseArr2,
                                               uint32_t* __restrict__ jcnt) {
  __shared__ uint32_t wsum[4];
  const int b = blockIdx.x, d = threadIdx.x;
  jcnt[b * 256 + d] = 0;
  uint32_t h = 0;
  if (d < NHEAD) { h = cnt2[b * 256 + d]; if (h > BCAP) h = BCAP; }
  const uint32_t excl = block_excl_scan(h, d, wsum);
  if (d < NHEAD) baseArr2[b * NHEAD + d] = excl;
}

// two-level counting-rank of round-2 head buckets: rec = (key32<<32)|(i<<16)|j.
// Rank by (digit2, key_low16, i) == stable sort; emit (j<<16)|q into j-buckets.
__global__ __launch_bounds__(256) void finalize_rank(const uint64_t* __restrict__ CVfix,
                                                     const uint32_t* __restrict__ cnt2,
                                                     const uint32_t* __restrict__ baseArr2,
                                                     uint32_t* __restrict__ jcnt,
                                                     uint32_t* __restrict__ jb) {
  __shared__ uint32_t sub[BCAP];
  __shared__ uint16_t dg[BCAP];
  __shared__ uint16_t idxt[BCAP];
  __shared__ uint32_t hist[256];
  __shared__ uint32_t cur[256];
  __shared__ uint32_t base2[257];
  __shared__ uint32_t wsum[4];
  const int t = threadIdx.x, u = blockIdx.x, b = blockIdx.y;
  const uint32_t base = baseArr2[b * NHEAD + u];
  if (base >= K_SZ) return;
  uint32_t n = cnt2[b * 256 + u];
  if (n > BCAP) n = BCAP;
  const uint64_t* __restrict__ g = CVfix + ((size_t)(b * NHEAD + u)) * BCAP;

  hist[t] = 0; __syncthreads();
  uint64_t rec[2] = {0, 0};
#pragma unroll
  for (int w = 0; w < 2; ++w) {
    const int e = t + w * 256;
    if (e < (int)n) {
      rec[w] = g[e];
      const uint32_t key = (uint32_t)(rec[w] >> 32);
      const uint32_t d = (key >> 16) & 0xFFu;
      sub[e] = ((key & 0xFFFFu) << 16) | (uint32_t)((rec[w] >> 16) & 0xFFFFull);
      dg[e] = (uint16_t)d;
      atomicAdd(&hist[d], 1u);
    }
  }
  __syncthreads();
  const uint32_t h = hist[t];
  const uint32_t excl = block_excl_scan(h, t, wsum);
  base2[t] = excl;
  cur[t] = excl;
  if (t == 255) base2[256] = excl + h;
  __syncthreads();
#pragma unroll
  for (int w = 0; w < 2; ++w) {
    const int e = t + w * 256;
    if (e < (int)n) idxt[atomicAdd(&cur[dg[e]], 1u)] = (uint16_t)e;
  }
  __syncthreads();
#pragma unroll
  for (int w = 0; w < 2; ++w) {
    const int e = t + w * 256;
    if (e < (int)n) {
      const uint32_t d = dg[e], s = sub[e];
      const uint32_t lo = base2[d], hi = base2[d + 1];
      uint32_t r = 0;
      for (uint32_t i = lo; i < hi; ++i) r += (sub[idxt[i]] < s) ? 1u : 0u;
      const uint32_t q = base + lo + r;
      if (q < K_SZ) {
        const uint32_t j = (uint32_t)(rec[w] & 0xFFFFull);   // permutation value
        const uint32_t slot = atomicAdd(&jcnt[b * 256 + (j >> 8)], 1u);
        if (slot < JCAP)
          jb[((size_t)b * 256 + (j >> 8)) * JCAP + slot] = (j << 16) | q;
      }
    }
  }
}

// compact capped j-buckets into dense bucket-ordered pair list sp[b][0..K).
__global__ __launch_bounds__(256) void compact_pairs(const uint32_t* __restrict__ jcnt,
                                                     const uint32_t* __restrict__ jb,
                                                     uint32_t* __restrict__ sp) {
  __shared__ uint32_t wsum[4];
  const int b = blockIdx.x, t = threadIdx.x;
  uint32_t c = jcnt[b * 256 + t];
  if (c > JCAP) c = JCAP;
  const uint32_t base = block_excl_scan(c, t, wsum);
  const uint32_t* __restrict__ src = jb + ((size_t)b * 256 + t) * JCAP;
  uint32_t* __restrict__ dst = sp + (size_t)b * K_SZ + base;
  for (uint32_t i = 0; i < c; ++i) dst[i] = src[i];
}

// gather: one (b,c) row per block. Random LDS writes, coalesced float4 stores.
__global__ __launch_bounds__(256) void gather_staged(const float* __restrict__ x,
                                                     const uint32_t* __restrict__ sp,
                                                     float* __restrict__ y) {
  __shared__ float row[K_SZ];   // 32 KiB
  const int t = threadIdx.x, c = blockIdx.x, b = blockIdx.y;
  const uint32_t* __restrict__ spb = sp + (size_t)b * K_SZ;
  const float* __restrict__ xr = x + ((size_t)b * C_SZ + c) * N_SZ;
#pragma unroll 8
  for (int w = 0; w < 32; ++w) {
    const uint32_t p = spb[w * 256 + t];
    row[p & 0xFFFFu] = xr[p >> 16];
  }
  __syncthreads();
  float4* __restrict__ yr4 = (float4*)(y + ((size_t)b * C_SZ + c) * K_SZ);
  const float4* __restrict__ r4 = (const float4*)row;
#pragma unroll
  for (int w = 0; w < 8; ++w) yr4[w * 256 + t] = r4[w * 256 + t];
}

extern "C" void kernel_launch(void* const* d_in, const int* in_sizes, int n_in,
                              void* d_out, int out_size, void* d_ws, size_t ws_size,
                              hipStream_t stream) {
  (void)in_sizes; (void)n_in; (void)out_size; (void)ws_size;
  const float* x = (const float*)d_in[0];
  float* y = (float*)d_out;

  // d_out (64 MiB) scratch; gather fully overwrites it and reads only x + d_ws.
  char* base = (char*)d_out;
  uint64_t* BVfix = (uint64_t*)base;                      // 24 MiB fixed-cap round-1 buckets
  uint64_t* CVfix = (uint64_t*)(base + (26u << 20));      // 4.5 MiB fixed-cap round-2 head buckets
  uint16_t* S1v   = (uint16_t*)(base + (31u << 20));      // 4 MiB u16 value table
  uint32_t* baseArr  = (uint32_t*)(base + (36u << 20));   // 33 KiB
  uint32_t* baseArr2 = (uint32_t*)(base + (37u << 20));   // 6 KiB
  // d_ws: [cnt1 32K | cnt2 32K | jcnt 32K | pad | jb | sp]
  uint32_t* cnt1 = (uint32_t*)d_ws;
  uint32_t* cnt2 = (uint32_t*)((char*)d_ws + (32u << 10));
  uint32_t* jcnt = (uint32_t*)((char*)d_ws + (64u << 10));
  uint32_t* jb   = (uint32_t*)((char*)d_ws + (128u << 10));   // 2.62 MiB
  uint32_t* sp   = (uint32_t*)((char*)d_ws + (4u << 20));     // 1 MiB

  const dim3 blk(256);
  const dim3 ggen(16, B_SZ);

  zero_cnt<<<dim3(B_SZ), blk, 0, stream>>>(cnt1);
  // round 1
  gen_scatter1<<<ggen, blk, 0, stream>>>(BVfix, cnt1);
  prefix1<<<dim3(B_SZ), blk, 0, stream>>>(cnt1, baseArr, cnt2);
  rank_sort1<<<dim3(256, B_SZ), blk, 0, stream>>>(BVfix, cnt1, baseArr, S1v);
  // round 2
  gen_scatter2<<<ggen, blk, 0, stream>>>(S1v, CVfix, cnt2);
  prefix2<<<dim3(B_SZ), blk, 0, stream>>>(cnt2, baseArr2, jcnt);
  finalize_rank<<<dim3(NHEAD, B_SZ), blk, 0, stream>>>(CVfix, cnt2, baseArr2, jcnt, jb);
  compact_pairs<<<dim3(B_SZ), blk, 0, stream>>>(jcnt, jb, sp);
  // gather
  gather_staged<<<dim3(C_SZ, B_SZ), blk, 0, stream>>>(x, sp, y);
}

// Round 11
// 187.037 us; speedup vs baseline: 1.3334x; 1.0339x over previous
//
#include <hip/hip_runtime.h>
#include <stdint.h>

#define B_SZ 32
#define C_SZ 64
#define N_SZ 65536
#define K_SZ 8192
#define BCAP 384   // fixed per-bucket capacity (Poisson(256), ~8 sigma; verified)
#define NHEAD 48   // head buckets for round 2 (verified: base(48) >= K)
#define JCAP 80    // per j-bucket capacity (verified no overflow)

__device__ __forceinline__ uint32_t rotl32(uint32_t v, int r) {
  return (v << r) | (v >> (32 - r));
}

// JAX Threefry-2x32, 20 rounds.
__device__ __forceinline__ void threefry2x32(uint32_t k0, uint32_t k1,
                                             uint32_t x0, uint32_t x1,
                                             uint32_t& o0, uint32_t& o1) {
  const uint32_t ks2 = k0 ^ k1 ^ 0x1BD11BDAu;
  x0 += k0; x1 += k1;
#define TF_R(r) { x0 += x1; x1 = rotl32(x1, (r)); x1 ^= x0; }
  TF_R(13) TF_R(15) TF_R(26) TF_R(6)   x0 += k1;  x1 += ks2 + 1u;
  TF_R(17) TF_R(29) TF_R(16) TF_R(24)  x0 += ks2; x1 += k0  + 2u;
  TF_R(13) TF_R(15) TF_R(26) TF_R(6)   x0 += k0;  x1 += k1  + 3u;
  TF_R(17) TF_R(29) TF_R(16) TF_R(24)  x0 += k1;  x1 += ks2 + 4u;
  TF_R(13) TF_R(15) TF_R(26) TF_R(6)   x0 += ks2; x1 += k0  + 5u;
#undef TF_R
  o0 = x0; o1 = x1;
}

__device__ __forceinline__ void subkey_for_round(int b, int round,
                                                 uint32_t& sk0, uint32_t& sk1) {
  uint32_t c0, c1;
  threefry2x32(0u, 1u, 0u, (uint32_t)b, c0, c1);
  for (int r = 0; r < round; ++r) {
    uint32_t n0, n1;
    threefry2x32(c0, c1, 0u, 0u, n0, n1);
    c0 = n0; c1 = n1;
  }
  threefry2x32(c0, c1, 0u, 1u, sk0, sk1);
}

// 256-wide exclusive scan using per-wave shfl scans + 1 barrier.
// NOTE: caller must have >=1 __syncthreads() between two calls (wsum reuse).
__device__ __forceinline__ uint32_t block_excl_scan(uint32_t h, int t,
                                                    uint32_t* __restrict__ wsum) {
  const int lane = t & 63, w = t >> 6;
  uint32_t inc = h;
#pragma unroll
  for (int off = 1; off < 64; off <<= 1) {
    const uint32_t y = __shfl_up(inc, off, 64);
    if (lane >= off) inc += y;
  }
  if (lane == 63) wsum[w] = inc;
  __syncthreads();
  uint32_t woff = 0;
#pragma unroll
  for (int w2 = 0; w2 < 4; ++w2)
    if (w2 < w) woff += wsum[w2];
  return woff + inc - h;
}

// zero cnt1|cnt2|jcnt (contiguous 96 KiB in d_ws).
__global__ __launch_bounds__(256) void zero_cnt(uint32_t* __restrict__ z) {
  z[blockIdx.x * 256 + threadIdx.x] = 0;
}

// round-1: keygen (recomputed, nothing staged) + direct fixed-cap bucket scatter.
__global__ __launch_bounds__(256) void gen_scatter1(uint64_t* __restrict__ BVfix,
                                                    uint32_t* __restrict__ cnt1) {
  __shared__ uint32_t lcnt[256];
  __shared__ uint32_t gb[256];
  const int t = threadIdx.x, chunk = blockIdx.x, b = blockIdx.y;
  lcnt[t] = 0; __syncthreads();
  uint32_t sk0, sk1;
  subkey_for_round(b, 0, sk0, sk1);
  uint64_t v[16]; uint32_t r[16], dg[16];
  const int base = chunk * 4096;
#pragma unroll
  for (int e = 0; e < 16; ++e) {
    const int i = base + e * 256 + t;
    uint32_t o0, o1;
    threefry2x32(sk0, sk1, 0u, (uint32_t)i, o0, o1);
    const uint32_t bits = o0 ^ o1;
    v[e] = ((uint64_t)bits << 16) | (uint64_t)i;
    dg[e] = bits >> 24;
    r[e] = atomicAdd(&lcnt[dg[e]], 1u);
  }
  __syncthreads();
  if (lcnt[t]) gb[t] = atomicAdd(&cnt1[b * 256 + t], lcnt[t]);
  __syncthreads();
#pragma unroll
  for (int e = 0; e < 16; ++e) {
    const uint32_t slot = gb[dg[e]] + r[e];
    if (slot < BCAP)
      BVfix[((size_t)(b * 256 + dg[e])) * BCAP + slot] = v[e];
  }
}

// Two-level counting-rank of one bucket (n<=BCAP). In-block prefix over the
// batch's 256 cnt1 entries gives this bucket's output base (no prefix kernel).
// digit2 = key bits 23..16; within group rank by (key_low16<<16)|pos.
// Order == stable sort by full key (pos tiebreak). Writes S1v[rank] = pos.
__global__ __launch_bounds__(256) void rank_sort1(const uint64_t* __restrict__ BVfix,
                                                  const uint32_t* __restrict__ cnt1,
                                                  uint16_t* __restrict__ S1v) {
  __shared__ uint32_t sub[BCAP];
  __shared__ uint16_t dg[BCAP];
  __shared__ uint16_t idxt[BCAP];
  __shared__ uint32_t hist[256];
  __shared__ uint32_t cur[256];
  __shared__ uint32_t base2[257];
  __shared__ uint32_t wsum[4];
  __shared__ uint32_t sh_bn[2];
  const int t = threadIdx.x, u = blockIdx.x, b = blockIdx.y;

  // in-block scan of cnt1 row -> this bucket's base and count
  {
    uint32_t hh = cnt1[b * 256 + t];
    if (hh > BCAP) hh = BCAP;
    const uint32_t excl0 = block_excl_scan(hh, t, wsum);
    if (t == u) { sh_bn[0] = excl0; sh_bn[1] = hh; }
  }
  __syncthreads();
  const uint32_t base = sh_bn[0];
  const uint32_t n = sh_bn[1];
  const uint64_t* __restrict__ g = BVfix + ((size_t)(b * 256 + u)) * BCAP;

  hist[t] = 0; __syncthreads();
  uint64_t rec[2] = {0, 0};
#pragma unroll
  for (int w = 0; w < 2; ++w) {
    const int e = t + w * 256;
    if (e < (int)n) {
      rec[w] = g[e];
      const uint32_t key = (uint32_t)(rec[w] >> 16);
      const uint32_t d = (key >> 16) & 0xFFu;
      sub[e] = ((key & 0xFFFFu) << 16) | (uint32_t)(rec[w] & 0xFFFFull);
      dg[e] = (uint16_t)d;
      atomicAdd(&hist[d], 1u);
    }
  }
  __syncthreads();
  const uint32_t h = hist[t];
  const uint32_t excl = block_excl_scan(h, t, wsum);
  base2[t] = excl;
  cur[t] = excl;
  if (t == 255) base2[256] = excl + h;
  __syncthreads();
#pragma unroll
  for (int w = 0; w < 2; ++w) {
    const int e = t + w * 256;
    if (e < (int)n) idxt[atomicAdd(&cur[dg[e]], 1u)] = (uint16_t)e;
  }
  __syncthreads();
  uint16_t* __restrict__ out = S1v + (size_t)b * N_SZ + base;
#pragma unroll
  for (int w = 0; w < 2; ++w) {
    const int e = t + w * 256;
    if (e < (int)n) {
      const uint32_t d = dg[e], s = sub[e];
      const uint32_t lo = base2[d], hi = base2[d + 1];
      uint32_t r = 0;
      for (uint32_t i = lo; i < hi; ++i) r += (sub[idxt[i]] < s) ? 1u : 0u;
      out[lo + r] = (uint16_t)(rec[w] & 0xFFFFull);
    }
  }
}

// round-2: keygen + direct scatter of head buckets (u < NHEAD) only.
// rec = (key32<<32) | (i<<16) | j : i is the STABLE TIEBREAK (matches JAX
// stable sort); j = S1v[i] (coalesced read) rides along for finalize.
__global__ __launch_bounds__(256) void gen_scatter2(const uint16_t* __restrict__ S1v,
                                                    uint64_t* __restrict__ CVfix,
                                                    uint32_t* __restrict__ cnt2) {
  __shared__ uint32_t lcnt[256];
  __shared__ uint32_t gb[256];
  const int t = threadIdx.x, chunk = blockIdx.x, b = blockIdx.y;
  lcnt[t] = 0; __syncthreads();
  uint32_t sk0, sk1;
  subkey_for_round(b, 1, sk0, sk1);
  const uint16_t* __restrict__ s1 = S1v + (size_t)b * N_SZ;
  uint64_t v[16]; uint32_t r[16], dg[16];
  const int base = chunk * 4096;
#pragma unroll
  for (int e = 0; e < 16; ++e) {
    const int i = base + e * 256 + t;
    uint32_t o0, o1;
    threefry2x32(sk0, sk1, 0u, (uint32_t)i, o0, o1);
    const uint32_t bits = o0 ^ o1;
    dg[e] = bits >> 24;
    if (dg[e] < NHEAD) {
      v[e] = ((uint64_t)bits << 32) | ((uint64_t)(uint32_t)i << 16) | (uint64_t)s1[i];
      r[e] = atomicAdd(&lcnt[dg[e]], 1u);
    }
  }
  __syncthreads();
  if (t < NHEAD && lcnt[t]) gb[t] = atomicAdd(&cnt2[b * 256 + t], lcnt[t]);
  __syncthreads();
#pragma unroll
  for (int e = 0; e < 16; ++e) {
    if (dg[e] < NHEAD) {
      const uint32_t slot = gb[dg[e]] + r[e];
      if (slot < BCAP)
        CVfix[((size_t)(b * NHEAD + dg[e])) * BCAP + slot] = v[e];
    }
  }
}

// rank round-2 head buckets (in-block prefix over NHEAD counts);
// rank by (digit2, key_low16, i) == stable sort; emit (j<<16)|q into j-buckets.
__global__ __launch_bounds__(256) void finalize_rank(const uint64_t* __restrict__ CVfix,
                                                     const uint32_t* __restrict__ cnt2,
                                                     uint32_t* __restrict__ jcnt,
                                                     uint32_t* __restrict__ jb) {
  __shared__ uint32_t sub[BCAP];
  __shared__ uint16_t dg[BCAP];
  __shared__ uint16_t idxt[BCAP];
  __shared__ uint32_t hist[256];
  __shared__ uint32_t cur[256];
  __shared__ uint32_t base2[257];
  __shared__ uint32_t wsum[4];
  __shared__ uint32_t sh_bn[2];
  const int t = threadIdx.x, u = blockIdx.x, b = blockIdx.y;

  {
    uint32_t hh = 0;
    if (t < NHEAD) { hh = cnt2[b * 256 + t]; if (hh > BCAP) hh = BCAP; }
    const uint32_t excl0 = block_excl_scan(hh, t, wsum);
    if (t == u) { sh_bn[0] = excl0; sh_bn[1] = hh; }
  }
  __syncthreads();
  const uint32_t base = sh_bn[0];
  if (base >= K_SZ) return;   // uniform per block
  const uint32_t n = sh_bn[1];
  const uint64_t* __restrict__ g = CVfix + ((size_t)(b * NHEAD + u)) * BCAP;

  hist[t] = 0; __syncthreads();
  uint64_t rec[2] = {0, 0};
#pragma unroll
  for (int w = 0; w < 2; ++w) {
    const int e = t + w * 256;
    if (e < (int)n) {
      rec[w] = g[e];
      const uint32_t key = (uint32_t)(rec[w] >> 32);
      const uint32_t d = (key >> 16) & 0xFFu;
      sub[e] = ((key & 0xFFFFu) << 16) | (uint32_t)((rec[w] >> 16) & 0xFFFFull);
      dg[e] = (uint16_t)d;
      atomicAdd(&hist[d], 1u);
    }
  }
  __syncthreads();
  const uint32_t h = hist[t];
  const uint32_t excl = block_excl_scan(h, t, wsum);
  base2[t] = excl;
  cur[t] = excl;
  if (t == 255) base2[256] = excl + h;
  __syncthreads();
#pragma unroll
  for (int w = 0; w < 2; ++w) {
    const int e = t + w * 256;
    if (e < (int)n) idxt[atomicAdd(&cur[dg[e]], 1u)] = (uint16_t)e;
  }
  __syncthreads();
#pragma unroll
  for (int w = 0; w < 2; ++w) {
    const int e = t + w * 256;
    if (e < (int)n) {
      const uint32_t d = dg[e], s = sub[e];
      const uint32_t lo = base2[d], hi = base2[d + 1];
      uint32_t r = 0;
      for (uint32_t i = lo; i < hi; ++i) r += (sub[idxt[i]] < s) ? 1u : 0u;
      const uint32_t q = base + lo + r;
      if (q < K_SZ) {
        const uint32_t j = (uint32_t)(rec[w] & 0xFFFFull);   // permutation value
        const uint32_t slot = atomicAdd(&jcnt[b * 256 + (j >> 8)], 1u);
        if (slot < JCAP)
          jb[((size_t)b * 256 + (j >> 8)) * JCAP + slot] = (j << 16) | q;
      }
    }
  }
}

// compact capped j-buckets into dense bucket-ordered pair list sp[b][0..K).
// Item-parallel: build k->bucket map in LDS, then coalesced copy.
__global__ __launch_bounds__(256) void compact_pairs(const uint32_t* __restrict__ jcnt,
                                                     const uint32_t* __restrict__ jb,
                                                     uint32_t* __restrict__ sp) {
  __shared__ uint32_t bases[256];
  __shared__ uint8_t map8[K_SZ];   // 8 KiB
  __shared__ uint32_t wsum[4];
  const int b = blockIdx.x, t = threadIdx.x;
  uint32_t c = jcnt[b * 256 + t];
  if (c > JCAP) c = JCAP;
  const uint32_t excl = block_excl_scan(c, t, wsum);
  bases[t] = excl;
  for (uint32_t i = 0; i < c; ++i)
    if (excl + i < K_SZ) map8[excl + i] = (uint8_t)t;
  __syncthreads();
  const uint32_t* __restrict__ jbb = jb + (size_t)b * 256 * JCAP;
  uint32_t* __restrict__ dst = sp + (size_t)b * K_SZ;
#pragma unroll 8
  for (int k = t; k < K_SZ; k += 256) {
    const uint32_t d = map8[k];
    dst[k] = jbb[d * JCAP + (k - bases[d])];
  }
}

// gather: one (b,c) row per block. Random LDS writes, coalesced float4 stores.
__global__ __launch_bounds__(256) void gather_staged(const float* __restrict__ x,
                                                     const uint32_t* __restrict__ sp,
                                                     float* __restrict__ y) {
  __shared__ float row[K_SZ];   // 32 KiB
  const int t = threadIdx.x, c = blockIdx.x, b = blockIdx.y;
  const uint32_t* __restrict__ spb = sp + (size_t)b * K_SZ;
  const float* __restrict__ xr = x + ((size_t)b * C_SZ + c) * N_SZ;
#pragma unroll 8
  for (int w = 0; w < 32; ++w) {
    const uint32_t p = spb[w * 256 + t];
    row[p & 0xFFFFu] = xr[p >> 16];
  }
  __syncthreads();
  float4* __restrict__ yr4 = (float4*)(y + ((size_t)b * C_SZ + c) * K_SZ);
  const float4* __restrict__ r4 = (const float4*)row;
#pragma unroll
  for (int w = 0; w < 8; ++w) yr4[w * 256 + t] = r4[w * 256 + t];
}

extern "C" void kernel_launch(void* const* d_in, const int* in_sizes, int n_in,
                              void* d_out, int out_size, void* d_ws, size_t ws_size,
                              hipStream_t stream) {
  (void)in_sizes; (void)n_in; (void)out_size; (void)ws_size;
  const float* x = (const float*)d_in[0];
  float* y = (float*)d_out;

  // d_out (64 MiB) scratch; gather fully overwrites it and reads only x + d_ws.
  char* base = (char*)d_out;
  uint64_t* BVfix = (uint64_t*)base;                      // 24 MiB fixed-cap round-1 buckets
  uint64_t* CVfix = (uint64_t*)(base + (26u << 20));      // 4.5 MiB fixed-cap round-2 head buckets
  uint16_t* S1v   = (uint16_t*)(base + (31u << 20));      // 4 MiB u16 value table
  // d_ws: [cnt1 32K | cnt2 32K | jcnt 32K | pad | jb | sp]
  uint32_t* cnt1 = (uint32_t*)d_ws;
  uint32_t* cnt2 = (uint32_t*)((char*)d_ws + (32u << 10));
  uint32_t* jcnt = (uint32_t*)((char*)d_ws + (64u << 10));
  uint32_t* jb   = (uint32_t*)((char*)d_ws + (128u << 10));   // 2.62 MiB
  uint32_t* sp   = (uint32_t*)((char*)d_ws + (4u << 20));     // 1 MiB

  const dim3 blk(256);
  const dim3 ggen(16, B_SZ);

  zero_cnt<<<dim3(96), blk, 0, stream>>>(cnt1);   // cnt1+cnt2+jcnt contiguous
  // round 1
  gen_scatter1<<<ggen, blk, 0, stream>>>(BVfix, cnt1);
  rank_sort1<<<dim3(256, B_SZ), blk, 0, stream>>>(BVfix, cnt1, S1v);
  // round 2
  gen_scatter2<<<ggen, blk, 0, stream>>>(S1v, CVfix, cnt2);
  finalize_rank<<<dim3(NHEAD, B_SZ), blk, 0, stream>>>(CVfix, cnt2, jcnt, jb);
  compact_pairs<<<dim3(B_SZ), blk, 0, stream>>>(jcnt, jb, sp);
  // gather
  gather_staged<<<dim3(C_SZ, B_SZ), blk, 0, stream>>>(x, sp, y);
}